// Round 3
// baseline (511.192 us; speedup 1.0000x reference)
//
#include <hip/hip_runtime.h>
#include <hip/hip_bf16.h>

#define H 32
#define HKV 8
#define DD 128
#define SMAX 1024
#define QBLK 32            // q rows per wave (per head)
#define KVBLK 64
#define NQB (SMAX / QBLK)  // 32
#define QSCALE 0.12751770f // (1/sqrt(128)) * log2(e) — exp2-domain softmax

typedef __attribute__((ext_vector_type(8))) short bf16x8;
typedef __attribute__((ext_vector_type(4))) short bf16x4;
typedef __attribute__((ext_vector_type(4))) float f32x4;
typedef __attribute__((ext_vector_type(4))) unsigned short u16x4;

__device__ inline unsigned short f2bf(float f) {
  unsigned u = __float_as_uint(f);
  unsigned r = 0x7fffu + ((u >> 16) & 1u);
  return (unsigned short)((u + r) >> 16);
}

// XOR swizzle with bit-3 term: spreads 64 lanes across the bank floor for
// b64 reads (4 lanes/8B-slot = wave64 minimum). Bits 3..6 only, rows stay
// 8B-aligned so all reads are ds_read_b64 pairs.
__device__ inline int swz(int r) {
  return ((r & 7) << 4) | (((r >> 3) & 1) << 3);
}

__global__ __launch_bounds__(256, 2) void fa_kernel(
    const float* __restrict__ q, const float* __restrict__ k,
    const float* __restrict__ v, const int* __restrict__ cu,
    float* __restrict__ out, int inner_n) {
  const int bx = blockIdx.x;
  const int inner = bx % inner_n;
  const int qb = NQB - 1 - (bx / inner_n);  // big q-blocks dispatch first
  const int b = inner / HKV;
  const int kvh = inner % HKV;

  const int seq_start = cu[b];
  const int seq_len = cu[b + 1] - seq_start;
  if (qb * QBLK >= seq_len) return;

  const int tid = threadIdx.x;
  const int lane = tid & 63;
  const int w = tid >> 6;
  const int lg = lane >> 4;
  const int lr = lane & 15;
  const int h = kvh * (H / HKV) + w;  // wave w owns head kvh*4+w

  __shared__ __align__(16) char kbuf[2][KVBLK * DD * 2];       // [64 kv][128 d]
  __shared__ __align__(16) char vbuf[2][DD * KVBLK * 2];       // [128 d][64 kv] V^T
  __shared__ __align__(16) char pbuf[4][QBLK * KVBLK * 2];     // per-wave [32][64]

  const float* kbase = k + (size_t)seq_start * (HKV * DD) + kvh * DD;
  const float* vbase = v + (size_t)seq_start * (HKV * DD) + kvh * DD;

  float4 kreg[8], vreg[8];

#define LOAD_T(T)                                                       \
  do {                                                                  \
    int rbase_ = (T)*KVBLK;                                             \
    _Pragma("unroll") for (int i = 0; i < 8; ++i) {                     \
      int f4_ = i * 256 + tid;                                          \
      int row_ = f4_ >> 5;                                              \
      int c4_ = f4_ & 31;                                               \
      size_t off_ =                                                     \
          (size_t)min(rbase_ + row_, seq_len - 1) * (HKV * DD) + c4_ * 4; \
      kreg[i] = *(const float4*)(kbase + off_);                         \
      vreg[i] = *(const float4*)(vbase + off_);                         \
    }                                                                   \
  } while (0)

#define STORE_T(BI)                                                     \
  do {                                                                  \
    char* kb_ = kbuf[BI];                                               \
    char* vb_ = vbuf[BI];                                               \
    _Pragma("unroll") for (int i = 0; i < 8; ++i) {                     \
      int f4_ = i * 256 + tid;                                          \
      int row_ = f4_ >> 5;                                              \
      int c4_ = f4_ & 31;                                               \
      u16x4 hh_;                                                        \
      hh_[0] = f2bf(kreg[i].x); hh_[1] = f2bf(kreg[i].y);               \
      hh_[2] = f2bf(kreg[i].z); hh_[3] = f2bf(kreg[i].w);               \
      *(u16x4*)(kb_ + row_ * 256 + ((c4_ * 8) ^ swz(row_))) = hh_;      \
      unsigned short v0_ = f2bf(vreg[i].x), v1_ = f2bf(vreg[i].y);      \
      unsigned short v2_ = f2bf(vreg[i].z), v3_ = f2bf(vreg[i].w);      \
      int d0_ = 4 * c4_;                                                \
      *(unsigned short*)(vb_ + (d0_ + 0) * 128 + ((row_ * 2) ^ swz(d0_ + 0))) = v0_; \
      *(unsigned short*)(vb_ + (d0_ + 1) * 128 + ((row_ * 2) ^ swz(d0_ + 1))) = v1_; \
      *(unsigned short*)(vb_ + (d0_ + 2) * 128 + ((row_ * 2) ^ swz(d0_ + 2))) = v2_; \
      *(unsigned short*)(vb_ + (d0_ + 3) * 128 + ((row_ * 2) ^ swz(d0_ + 3))) = v3_; \
    }                                                                   \
  } while (0)

  // ---- issue tile-0 loads first; Q frag load overlaps their latency ----
  LOAD_T(0);

  bf16x8 qf[2][4];  // Q * (scale*log2e) in bf16; row=lr, k=8*lg+32*ks+[0..7]
#pragma unroll
  for (int m = 0; m < 2; ++m) {
    int q_pos = qb * QBLK + m * 16 + lr;
    int q_tok = seq_start + min(q_pos, seq_len - 1);
    const float* qp = q + (size_t)q_tok * (H * DD) + h * DD;
#pragma unroll
    for (int ks = 0; ks < 4; ++ks) {
      int d0 = 8 * lg + 32 * ks;
      float4 x = *(const float4*)(qp + d0);
      float4 y = *(const float4*)(qp + d0 + 4);
      bf16x8 tq;
      tq[0] = (short)f2bf(x.x * QSCALE); tq[1] = (short)f2bf(x.y * QSCALE);
      tq[2] = (short)f2bf(x.z * QSCALE); tq[3] = (short)f2bf(x.w * QSCALE);
      tq[4] = (short)f2bf(y.x * QSCALE); tq[5] = (short)f2bf(y.y * QSCALE);
      tq[6] = (short)f2bf(y.z * QSCALE); tq[7] = (short)f2bf(y.w * QSCALE);
      qf[m][ks] = tq;
    }
  }

  f32x4 o[2][8];
#pragma unroll
  for (int m = 0; m < 2; ++m)
#pragma unroll
    for (int i = 0; i < 8; ++i) o[m][i] = (f32x4){0.f, 0.f, 0.f, 0.f};
  float m_run[2][4], l_run[2][4];
#pragma unroll
  for (int m = 0; m < 2; ++m)
#pragma unroll
    for (int r = 0; r < 4; ++r) { m_run[m][r] = -1e30f; l_run[m][r] = 0.f; }

  char* pw = pbuf[w];
  const int qmax = qb * QBLK + QBLK - 1;
  const int tmax = qmax >> 6;

  STORE_T(0);
  __syncthreads();

  for (int t = 0; t <= tmax; ++t) {
    const int cur = t & 1;
    if (t < tmax) LOAD_T(t + 1);  // async prefetch: latency hides under compute
    __builtin_amdgcn_sched_barrier(0);

    const char* kb_ = kbuf[cur];
    const char* vb_ = vbuf[cur];

    // ---- QK^T: S[32 q][64 kv]; skip n-tiles above the causal line ----
    f32x4 s[2][4];
    __builtin_amdgcn_s_setprio(1);
#pragma unroll
    for (int n = 0; n < 4; ++n) {
      if (t * 64 + n * 16 <= qmax) {
        int kcol = n * 16 + lr;
        int key = swz(kcol);
        bf16x8 kb4[4];
#pragma unroll
        for (int ks = 0; ks < 4; ++ks) {
          int a0 = kcol * 256 + ((16 * lg + 64 * ks) ^ key);
          bf16x4 lo = *(const bf16x4*)(kb_ + a0);
          bf16x4 hi = *(const bf16x4*)(kb_ + (a0 ^ 8));
          bf16x8 t8;
          t8[0] = lo[0]; t8[1] = lo[1]; t8[2] = lo[2]; t8[3] = lo[3];
          t8[4] = hi[0]; t8[5] = hi[1]; t8[6] = hi[2]; t8[7] = hi[3];
          kb4[ks] = t8;
        }
#pragma unroll
        for (int m = 0; m < 2; ++m) {
          f32x4 acc = {0.f, 0.f, 0.f, 0.f};
#pragma unroll
          for (int ks = 0; ks < 4; ++ks)
            acc = __builtin_amdgcn_mfma_f32_16x16x32_bf16(qf[m][ks], kb4[ks], acc, 0, 0, 0);
          s[m][n] = acc;
        }
      } else {
        s[0][n] = (f32x4){-2e30f, -2e30f, -2e30f, -2e30f};
        s[1][n] = s[0][n];
      }
    }
    __builtin_amdgcn_s_setprio(0);

    // ---- causal mask (diagonal tile only; scale already folded into Q) ----
    if (t == tmax) {
#pragma unroll
      for (int n = 0; n < 4; ++n) {
        int kv_pos = t * 64 + n * 16 + lr;
#pragma unroll
        for (int m = 0; m < 2; ++m) {
          int qrow = qb * QBLK + m * 16 + 4 * lg;
#pragma unroll
          for (int r = 0; r < 4; ++r)
            if (kv_pos > qrow + r) s[m][n][r] = -2e30f;
        }
      }
    }

    // ---- online softmax (exp2 domain) with defer-max rescale (T13) ----
#pragma unroll
    for (int m = 0; m < 2; ++m) {
      float mx[4];
#pragma unroll
      for (int r = 0; r < 4; ++r) {
        float v0 = fmaxf(fmaxf(s[m][0][r], s[m][1][r]), fmaxf(s[m][2][r], s[m][3][r]));
#pragma unroll
        for (int off = 1; off < 16; off <<= 1)
          v0 = fmaxf(v0, __shfl_xor(v0, off, 64));
        mx[r] = v0;
      }
      float need = mx[0] - m_run[m][0];
#pragma unroll
      for (int r = 1; r < 4; ++r) need = fmaxf(need, mx[r] - m_run[m][r]);
      if (!__all(need <= 10.0f)) {  // P bounded by 2^10, bf16/f32 tolerate
#pragma unroll
        for (int r = 0; r < 4; ++r) {
          float mn = fmaxf(m_run[m][r], mx[r]);
          float corr = exp2f(m_run[m][r] - mn);
          m_run[m][r] = mn;
          l_run[m][r] *= corr;
#pragma unroll
          for (int dt = 0; dt < 8; ++dt) o[m][dt][r] *= corr;
        }
      }
      float rsum[4] = {0.f, 0.f, 0.f, 0.f};
#pragma unroll
      for (int n = 0; n < 4; ++n) {
#pragma unroll
        for (int r = 0; r < 4; ++r) {
          float p = exp2f(s[m][n][r] - m_run[m][r]);
          rsum[r] += p;
          int prow = m * 16 + 4 * lg + r;
          int pcol = n * 16 + lr;
          *(unsigned short*)(pw + prow * 128 + ((pcol * 2) ^ swz(prow))) = f2bf(p);
        }
      }
#pragma unroll
      for (int r = 0; r < 4; ++r) {
        float rs = rsum[r];
#pragma unroll
        for (int off = 1; off < 16; off <<= 1)
          rs += __shfl_xor(rs, off, 64);
        l_run[m][r] += rs;
      }
    }

    // ---- PV: O[32 q][128 d] += P[32][64] * V[64][128]; skip dead half ----
    const int nks = (t * 64 + 32 <= qmax) ? 2 : 1;
    __builtin_amdgcn_s_setprio(1);
    for (int ks = 0; ks < nks; ++ks) {
      bf16x8 pa[2];
#pragma unroll
      for (int m = 0; m < 2; ++m) {
        int prow = m * 16 + lr;
        int a0 = prow * 128 + ((16 * lg + 64 * ks) ^ swz(prow));
        bf16x4 lo = *(const bf16x4*)(pw + a0);
        bf16x4 hi = *(const bf16x4*)(pw + (a0 ^ 8));
        bf16x8 t8;
        t8[0] = lo[0]; t8[1] = lo[1]; t8[2] = lo[2]; t8[3] = lo[3];
        t8[4] = hi[0]; t8[5] = hi[1]; t8[6] = hi[2]; t8[7] = hi[3];
        pa[m] = t8;
      }
#pragma unroll
      for (int dt = 0; dt < 8; ++dt) {
        int d = dt * 16 + lr;
        int a0 = d * 128 + ((16 * lg + 64 * ks) ^ swz(d));
        bf16x4 lo = *(const bf16x4*)(vb_ + a0);
        bf16x4 hi = *(const bf16x4*)(vb_ + (a0 ^ 8));
        bf16x8 vbf;
        vbf[0] = lo[0]; vbf[1] = lo[1]; vbf[2] = lo[2]; vbf[3] = lo[3];
        vbf[4] = hi[0]; vbf[5] = hi[1]; vbf[6] = hi[2]; vbf[7] = hi[3];
#pragma unroll
        for (int m = 0; m < 2; ++m)
          o[m][dt] = __builtin_amdgcn_mfma_f32_16x16x32_bf16(pa[m], vbf, o[m][dt], 0, 0, 0);
      }
    }
    __builtin_amdgcn_s_setprio(0);

    if (t < tmax) {
      STORE_T(cur ^ 1);   // vmcnt waits land here, ~2000 cyc after issue
      __syncthreads();    // ONE barrier per tile
    }
  }

  // ---- epilogue ----
#pragma unroll
  for (int m = 0; m < 2; ++m) {
#pragma unroll
    for (int r = 0; r < 4; ++r) {
      int qp_ = qb * QBLK + m * 16 + 4 * lg + r;
      if (qp_ < seq_len) {
        float inv_l = 1.0f / l_run[m][r];
        float* op = out + (size_t)(seq_start + qp_) * (H * DD) + h * DD + lr;
#pragma unroll
        for (int dt = 0; dt < 8; ++dt) op[dt * 16] = o[m][dt][r] * inv_l;
      }
    }
  }
#undef LOAD_T
#undef STORE_T
}

extern "C" void kernel_launch(void* const* d_in, const int* in_sizes, int n_in,
                              void* d_out, int out_size, void* d_ws, size_t ws_size,
                              hipStream_t stream) {
  const float* q = (const float*)d_in[0];
  const float* k = (const float*)d_in[1];
  const float* v = (const float*)d_in[2];
  const int* cu = (const int*)d_in[3];
  float* out = (float*)d_out;
  const int B = in_sizes[3] - 1;  // 4
  const int inner_n = B * HKV;    // 32
  dim3 grid(NQB * inner_n);       // 1024 blocks, qb descending-major
  fa_kernel<<<grid, 256, 0, stream>>>(q, k, v, cu, out, inner_n);
}

// Round 4
// 290.376 us; speedup vs baseline: 1.7604x; 1.7604x over previous
//
#include <hip/hip_runtime.h>
#include <hip/hip_bf16.h>

#define H 32
#define HKV 8
#define DD 128
#define SMAX 1024
#define QBLK 32            // q rows per wave (per head)
#define KVBLK 64
#define NQB (SMAX / QBLK)  // 32
#define QSCALE 0.12751770f // (1/sqrt(128)) * log2(e) — exp2-domain softmax

typedef __attribute__((ext_vector_type(8))) short bf16x8;
typedef __attribute__((ext_vector_type(4))) short bf16x4;
typedef __attribute__((ext_vector_type(4))) float f32x4;
typedef __attribute__((ext_vector_type(4))) unsigned short u16x4;

__device__ inline unsigned short f2bf(float f) {
  unsigned u = __float_as_uint(f);
  unsigned r = 0x7fffu + ((u >> 16) & 1u);
  return (unsigned short)((u + r) >> 16);
}

// Both-sides-conflict-free XOR swizzle (bits 3..6, 8B-granular):
//   key(x) = (x ^ (x>>3)) & 15.
// Read side (x = n*16+lr): key covers all 16 values over lr -> 16 slots.
// Write side (x = 4*c4+j): key covers 16 values over c4 (2 lanes each;
// x2 rows = 4 lanes/slot, distinct 2B in 8B -> 2 lanes/bank = free).
__device__ inline int swz(int x) { return ((x ^ (x >> 3)) & 15) << 3; }

__global__ __launch_bounds__(256) void fa_kernel(
    const float* __restrict__ q, const float* __restrict__ k,
    const float* __restrict__ v, const int* __restrict__ cu,
    float* __restrict__ out, int inner_n) {
  const int bx = blockIdx.x;
  const int inner = bx % inner_n;
  const int qb = NQB - 1 - (bx / inner_n);  // big q-blocks dispatch first
  const int b = inner / HKV;
  const int kvh = inner % HKV;

  const int seq_start = cu[b];
  const int seq_len = cu[b + 1] - seq_start;
  if (qb * QBLK >= seq_len) return;

  const int tid = threadIdx.x;
  const int lane = tid & 63;
  const int w = tid >> 6;
  const int lg = lane >> 4;
  const int lr = lane & 15;
  const int h = kvh * (H / HKV) + w;  // wave w owns head kvh*4+w

  __shared__ __align__(16) char kbuf[2][KVBLK * DD * 2];    // [64 kv][128 d]
  __shared__ __align__(16) char vbuf[2][DD * KVBLK * 2];    // [128 d][64 kv] V^T
  __shared__ __align__(16) char pbuf[4][QBLK * KVBLK * 2];  // per-wave [32][64]

  const float* kbase = k + (size_t)seq_start * (HKV * DD) + kvh * DD;
  const float* vbase = v + (size_t)seq_start * (HKV * DD) + kvh * DD;

  float4 reg[8];  // ONE shared staging register block (K-phase, then V-phase)
  const int srow = tid >> 3;        // 0..31: two kv-rows per 16 threads? no:
  // f4 slot decomposition: f4 = i*256 + tid; row = f4>>5, c4 = f4&31.

#define LOAD_T(BASE, T)                                                   \
  do {                                                                    \
    int rbase_ = (T)*KVBLK;                                               \
    _Pragma("unroll") for (int i = 0; i < 8; ++i) {                       \
      int f4_ = i * 256 + tid;                                            \
      int row_ = f4_ >> 5;                                                \
      int c4_ = f4_ & 31;                                                 \
      size_t off_ =                                                       \
          (size_t)min(rbase_ + row_, seq_len - 1) * (HKV * DD) + c4_ * 4; \
      reg[i] = *(const float4*)((BASE) + off_);                           \
    }                                                                     \
  } while (0)

#define STORE_K(BI)                                                       \
  do {                                                                    \
    char* kb_ = kbuf[BI];                                                 \
    _Pragma("unroll") for (int i = 0; i < 8; ++i) {                       \
      int f4_ = i * 256 + tid;                                            \
      int row_ = f4_ >> 5;                                                \
      int c4_ = f4_ & 31;                                                 \
      u16x4 hh_;                                                          \
      hh_[0] = f2bf(reg[i].x); hh_[1] = f2bf(reg[i].y);                   \
      hh_[2] = f2bf(reg[i].z); hh_[3] = f2bf(reg[i].w);                   \
      *(u16x4*)(kb_ + row_ * 256 + ((c4_ * 8) ^ swz(row_))) = hh_;        \
    }                                                                     \
  } while (0)

#define STORE_V(BI)                                                       \
  do {                                                                    \
    char* vb_ = vbuf[BI];                                                 \
    _Pragma("unroll") for (int i = 0; i < 8; ++i) {                       \
      int f4_ = i * 256 + tid;                                            \
      int row_ = f4_ >> 5;                                                \
      int c4_ = f4_ & 31;                                                 \
      unsigned short v0_ = f2bf(reg[i].x), v1_ = f2bf(reg[i].y);          \
      unsigned short v2_ = f2bf(reg[i].z), v3_ = f2bf(reg[i].w);          \
      int d0_ = 4 * c4_;                                                  \
      *(unsigned short*)(vb_ + (d0_ + 0) * 128 + ((row_ * 2) ^ swz(d0_ + 0))) = v0_; \
      *(unsigned short*)(vb_ + (d0_ + 1) * 128 + ((row_ * 2) ^ swz(d0_ + 1))) = v1_; \
      *(unsigned short*)(vb_ + (d0_ + 2) * 128 + ((row_ * 2) ^ swz(d0_ + 2))) = v2_; \
      *(unsigned short*)(vb_ + (d0_ + 3) * 128 + ((row_ * 2) ^ swz(d0_ + 3))) = v3_; \
    }                                                                     \
  } while (0)

  // ---- prologue: K(0) loads in flight while Q fragments load ----
  LOAD_T(kbase, 0);

  bf16x8 qf[2][4];  // Q * (scale*log2e); row=lr, k = 8*lg + 32*ks + [0..7]
#pragma unroll
  for (int m = 0; m < 2; ++m) {
    int q_pos = qb * QBLK + m * 16 + lr;
    int q_tok = seq_start + min(q_pos, seq_len - 1);
    const float* qp = q + (size_t)q_tok * (H * DD) + h * DD;
#pragma unroll
    for (int ks = 0; ks < 4; ++ks) {
      int d0 = 8 * lg + 32 * ks;
      float4 x = *(const float4*)(qp + d0);
      float4 y = *(const float4*)(qp + d0 + 4);
      bf16x8 tq;
      tq[0] = (short)f2bf(x.x * QSCALE); tq[1] = (short)f2bf(x.y * QSCALE);
      tq[2] = (short)f2bf(x.z * QSCALE); tq[3] = (short)f2bf(x.w * QSCALE);
      tq[4] = (short)f2bf(y.x * QSCALE); tq[5] = (short)f2bf(y.y * QSCALE);
      tq[6] = (short)f2bf(y.z * QSCALE); tq[7] = (short)f2bf(y.w * QSCALE);
      qf[m][ks] = tq;
    }
  }

  f32x4 o[2][8];
#pragma unroll
  for (int m = 0; m < 2; ++m)
#pragma unroll
    for (int i = 0; i < 8; ++i) o[m][i] = (f32x4){0.f, 0.f, 0.f, 0.f};
  float m_run[2][4], l_run[2][4];
#pragma unroll
  for (int m = 0; m < 2; ++m)
#pragma unroll
    for (int r = 0; r < 4; ++r) { m_run[m][r] = -1e30f; l_run[m][r] = 0.f; }

  char* pw = pbuf[w];
  const int qmax = qb * QBLK + QBLK - 1;
  const int tmax = qmax >> 6;

  STORE_K(0);
  LOAD_T(vbase, 0);
  STORE_V(0);
  __syncthreads();

  for (int t = 0; t <= tmax; ++t) {
    const int cur = t & 1;
    const int nxt = cur ^ 1;
    const char* kb_ = kbuf[cur];
    const char* vb_ = vbuf[cur];

    // ---- issue next K loads; latency hides under QK^T ----
    if (t < tmax) LOAD_T(kbase, t + 1);
    __builtin_amdgcn_sched_barrier(0);

    // ---- QK^T: S[32 q][64 kv]; masked n-tiles only on diagonal tile ----
    f32x4 s[2][4];
    __builtin_amdgcn_s_setprio(1);
#pragma unroll
    for (int n = 0; n < 4; ++n) {
      if (t * 64 + n * 16 <= qmax) {
        int kcol = n * 16 + lr;
        int key = swz(kcol);
        bf16x8 kb4[4];
#pragma unroll
        for (int ks = 0; ks < 4; ++ks) {
          int a0 = kcol * 256 + ((16 * lg + 64 * ks) ^ key);
          bf16x4 lo = *(const bf16x4*)(kb_ + a0);
          bf16x4 hi = *(const bf16x4*)(kb_ + (a0 ^ 8));
          bf16x8 t8;
          t8[0] = lo[0]; t8[1] = lo[1]; t8[2] = lo[2]; t8[3] = lo[3];
          t8[4] = hi[0]; t8[5] = hi[1]; t8[6] = hi[2]; t8[7] = hi[3];
          kb4[ks] = t8;
        }
#pragma unroll
        for (int m = 0; m < 2; ++m) {
          f32x4 acc = {0.f, 0.f, 0.f, 0.f};
#pragma unroll
          for (int ks = 0; ks < 4; ++ks)
            acc = __builtin_amdgcn_mfma_f32_16x16x32_bf16(qf[m][ks], kb4[ks], acc, 0, 0, 0);
          s[m][n] = acc;
        }
      } else {
        s[0][n] = (f32x4){-2e30f, -2e30f, -2e30f, -2e30f};
        s[1][n] = s[0][n];
      }
    }
    __builtin_amdgcn_s_setprio(0);

    // ---- drain K(t+1) into LDS[nxt]; issue V(t+1) loads ----
    if (t < tmax) {
      STORE_K(nxt);
      LOAD_T(vbase, t + 1);
    }
    __builtin_amdgcn_sched_barrier(0);

    // ---- causal mask (diagonal tile; scale already folded into Q) ----
    if (t == tmax) {
#pragma unroll
      for (int n = 0; n < 4; ++n) {
        int kv_pos = t * 64 + n * 16 + lr;
#pragma unroll
        for (int m = 0; m < 2; ++m) {
          int qrow = qb * QBLK + m * 16 + 4 * lg;
#pragma unroll
          for (int r = 0; r < 4; ++r)
            if (kv_pos > qrow + r) s[m][n][r] = -2e30f;
        }
      }
    }

    // ---- online softmax (exp2 domain) with defer-max (T13) ----
#pragma unroll
    for (int m = 0; m < 2; ++m) {
      float mx[4];
#pragma unroll
      for (int r = 0; r < 4; ++r) {
        float v0 = fmaxf(fmaxf(s[m][0][r], s[m][1][r]), fmaxf(s[m][2][r], s[m][3][r]));
#pragma unroll
        for (int off = 1; off < 16; off <<= 1)
          v0 = fmaxf(v0, __shfl_xor(v0, off, 64));
        mx[r] = v0;
      }
      float need = mx[0] - m_run[m][0];
#pragma unroll
      for (int r = 1; r < 4; ++r) need = fmaxf(need, mx[r] - m_run[m][r]);
      if (!__all(need <= 10.0f)) {  // P bounded by 2^10; f32 accum tolerates
#pragma unroll
        for (int r = 0; r < 4; ++r) {
          float mn = fmaxf(m_run[m][r], mx[r]);
          float corr = exp2f(m_run[m][r] - mn);
          m_run[m][r] = mn;
          l_run[m][r] *= corr;
#pragma unroll
          for (int dt = 0; dt < 8; ++dt) o[m][dt][r] *= corr;
        }
      }
      float rsum[4] = {0.f, 0.f, 0.f, 0.f};
#pragma unroll
      for (int n = 0; n < 4; ++n) {
#pragma unroll
        for (int r = 0; r < 4; ++r) {
          float p = exp2f(s[m][n][r] - m_run[m][r]);
          rsum[r] += p;
          int prow = m * 16 + 4 * lg + r;
          int pcol = n * 16 + lr;
          *(unsigned short*)(pw + prow * 128 + ((pcol * 2) ^ swz(prow))) = f2bf(p);
        }
      }
#pragma unroll
      for (int r = 0; r < 4; ++r) {
        float rs = rsum[r];
#pragma unroll
        for (int off = 1; off < 16; off <<= 1)
          rs += __shfl_xor(rs, off, 64);
        l_run[m][r] += rs;
      }
    }

    // ---- PV: O[32 q][128 d] += P[32][64] * V[64][128]; skip dead half ----
    const int nks = (t * 64 + 32 <= qmax) ? 2 : 1;
    __builtin_amdgcn_s_setprio(1);
    for (int ks = 0; ks < nks; ++ks) {
      bf16x8 pa[2];
#pragma unroll
      for (int m = 0; m < 2; ++m) {
        int prow = m * 16 + lr;
        int a0 = prow * 128 + ((16 * lg + 64 * ks) ^ swz(prow));
        bf16x4 lo = *(const bf16x4*)(pw + a0);
        bf16x4 hi = *(const bf16x4*)(pw + (a0 ^ 8));
        bf16x8 t8;
        t8[0] = lo[0]; t8[1] = lo[1]; t8[2] = lo[2]; t8[3] = lo[3];
        t8[4] = hi[0]; t8[5] = hi[1]; t8[6] = hi[2]; t8[7] = hi[3];
        pa[m] = t8;
      }
#pragma unroll
      for (int dt = 0; dt < 8; ++dt) {
        int d = dt * 16 + lr;
        int a0 = d * 128 + ((16 * lg + 64 * ks) ^ swz(d));
        bf16x4 lo = *(const bf16x4*)(vb_ + a0);
        bf16x4 hi = *(const bf16x4*)(vb_ + (a0 ^ 8));
        bf16x8 vbf;
        vbf[0] = lo[0]; vbf[1] = lo[1]; vbf[2] = lo[2]; vbf[3] = lo[3];
        vbf[4] = hi[0]; vbf[5] = hi[1]; vbf[6] = hi[2]; vbf[7] = hi[3];
#pragma unroll
        for (int m = 0; m < 2; ++m)
          o[m][dt] = __builtin_amdgcn_mfma_f32_16x16x32_bf16(pa[m], vbf, o[m][dt], 0, 0, 0);
      }
    }
    __builtin_amdgcn_s_setprio(0);

    // ---- drain V(t+1) into LDS[nxt]; ONE barrier per tile ----
    if (t < tmax) STORE_V(nxt);
    __syncthreads();
  }

  // ---- epilogue ----
#pragma unroll
  for (int m = 0; m < 2; ++m) {
#pragma unroll
    for (int r = 0; r < 4; ++r) {
      int qp_ = qb * QBLK + m * 16 + 4 * lg + r;
      if (qp_ < seq_len) {
        float inv_l = 1.0f / l_run[m][r];
        float* op = out + (size_t)(seq_start + qp_) * (H * DD) + h * DD + lr;
#pragma unroll
        for (int dt = 0; dt < 8; ++dt) op[dt * 16] = o[m][dt][r] * inv_l;
      }
    }
  }
#undef LOAD_T
#undef STORE_K
#undef STORE_V
}

extern "C" void kernel_launch(void* const* d_in, const int* in_sizes, int n_in,
                              void* d_out, int out_size, void* d_ws, size_t ws_size,
                              hipStream_t stream) {
  const float* q = (const float*)d_in[0];
  const float* k = (const float*)d_in[1];
  const float* v = (const float*)d_in[2];
  const int* cu = (const int*)d_in[3];
  float* out = (float*)d_out;
  const int B = in_sizes[3] - 1;  // 4
  const int inner_n = B * HKV;    // 32
  dim3 grid(NQB * inner_n);       // 1024 blocks, qb descending-major
  fa_kernel<<<grid, 256, 0, stream>>>(q, k, v, cu, out, inner_n);
}

// Round 5
// 252.142 us; speedup vs baseline: 2.0274x; 1.1516x over previous
//
#include <hip/hip_runtime.h>
#include <hip/hip_bf16.h>

#define H 32
#define HKV 8
#define DD 128
#define SMAX 1024
#define QBLK 32            // q rows per wave (per head)
#define KVBLK 64
#define NQB (SMAX / QBLK)  // 32
#define QSCALE 0.12751770f // (1/sqrt(128)) * log2(e) — exp2-domain softmax

typedef __attribute__((ext_vector_type(8))) short bf16x8;
typedef __attribute__((ext_vector_type(4))) short bf16x4;
typedef __attribute__((ext_vector_type(4))) float f32x4;
typedef __attribute__((ext_vector_type(4))) unsigned int u32x4;
typedef __attribute__((ext_vector_type(2))) unsigned int u32x2;

// HW packed f32->bf16 (RNE), 2 values per instruction. dst = {lo:a, hi:b}.
__device__ inline unsigned cvt_pk_bf16(float a, float b) {
  unsigned r;
  asm("v_cvt_pk_bf16_f32 %0, %1, %2" : "=v"(r) : "v"(a), "v"(b));
  return r;
}

// Both-sides-conflict-free XOR swizzle (bits 3..6, 8B-granular).
__device__ inline int swz(int x) { return ((x ^ (x >> 3)) & 15) << 3; }

__global__ __launch_bounds__(256) void fa_kernel(
    const float* __restrict__ q, const float* __restrict__ k,
    const float* __restrict__ v, const int* __restrict__ cu,
    float* __restrict__ out, int inner_n) {
  const int bx = blockIdx.x;
  const int inner = bx % inner_n;
  const int qb = NQB - 1 - (bx / inner_n);  // big q-blocks dispatch first
  const int b = inner / HKV;
  const int kvh = inner % HKV;

  const int seq_start = cu[b];
  const int seq_len = cu[b + 1] - seq_start;
  if (qb * QBLK >= seq_len) return;

  const int tid = threadIdx.x;
  const int lane = tid & 63;
  const int w = tid >> 6;
  const int lg = lane >> 4;
  const int lr = lane & 15;
  const int h = kvh * (H / HKV) + w;  // wave w owns head kvh*4+w

  __shared__ __align__(16) char kbuf[2][KVBLK * DD * 2];    // [64 kv][128 d]
  __shared__ __align__(16) char vbuf[2][DD * KVBLK * 2];    // [128 d][64 kv] V^T
  __shared__ __align__(16) char pbuf[4][QBLK * KVBLK * 2];  // per-wave [32 q][64 kv]

  const float* kbase = k + (size_t)seq_start * (HKV * DD) + kvh * DD;
  const float* vbase = v + (size_t)seq_start * (HKV * DD) + kvh * DD;

  float4 reg[8];  // ONE shared staging block (K-phase, then V-phase)

#define LOAD_T(BASE, T)                                                   \
  do {                                                                    \
    int rbase_ = (T)*KVBLK;                                               \
    _Pragma("unroll") for (int i = 0; i < 8; ++i) {                       \
      int f4_ = i * 256 + tid;                                            \
      int row_ = f4_ >> 5;                                                \
      int c4_ = f4_ & 31;                                                 \
      size_t off_ =                                                       \
          (size_t)min(rbase_ + row_, seq_len - 1) * (HKV * DD) + c4_ * 4; \
      reg[i] = *(const float4*)((BASE) + off_);                           \
    }                                                                     \
  } while (0)

#define STORE_K(BI)                                                       \
  do {                                                                    \
    char* kb_ = kbuf[BI];                                                 \
    _Pragma("unroll") for (int i = 0; i < 8; ++i) {                       \
      int f4_ = i * 256 + tid;                                            \
      int row_ = f4_ >> 5;                                                \
      int c4_ = f4_ & 31;                                                 \
      u32x2 u_;                                                           \
      u_[0] = cvt_pk_bf16(reg[i].x, reg[i].y);                            \
      u_[1] = cvt_pk_bf16(reg[i].z, reg[i].w);                            \
      *(u32x2*)(kb_ + row_ * 256 + ((c4_ * 8) ^ swz(row_))) = u_;         \
    }                                                                     \
  } while (0)

#define STORE_V(BI)                                                       \
  do {                                                                    \
    char* vb_ = vbuf[BI];                                                 \
    _Pragma("unroll") for (int i = 0; i < 8; ++i) {                       \
      int f4_ = i * 256 + tid;                                            \
      int row_ = f4_ >> 5;                                                \
      int c4_ = f4_ & 31;                                                 \
      unsigned ab_ = cvt_pk_bf16(reg[i].x, reg[i].y);                     \
      unsigned cd_ = cvt_pk_bf16(reg[i].z, reg[i].w);                     \
      int d0_ = 4 * c4_;                                                  \
      *(unsigned short*)(vb_ + (d0_ + 0) * 128 + ((row_ * 2) ^ swz(d0_ + 0))) = (unsigned short)ab_;         \
      *(unsigned short*)(vb_ + (d0_ + 1) * 128 + ((row_ * 2) ^ swz(d0_ + 1))) = (unsigned short)(ab_ >> 16); \
      *(unsigned short*)(vb_ + (d0_ + 2) * 128 + ((row_ * 2) ^ swz(d0_ + 2))) = (unsigned short)cd_;         \
      *(unsigned short*)(vb_ + (d0_ + 3) * 128 + ((row_ * 2) ^ swz(d0_ + 3))) = (unsigned short)(cd_ >> 16); \
    }                                                                     \
  } while (0)

  // ---- prologue: K(0) loads in flight while Q fragments load ----
  LOAD_T(kbase, 0);

  bf16x8 qf[2][4];  // Q * (scale*log2e); row=lr, k = 8*lg + 32*ks + [0..7]
#pragma unroll
  for (int m = 0; m < 2; ++m) {
    int q_pos = qb * QBLK + m * 16 + lr;
    int q_tok = seq_start + min(q_pos, seq_len - 1);
    const float* qp = q + (size_t)q_tok * (H * DD) + h * DD;
#pragma unroll
    for (int ks = 0; ks < 4; ++ks) {
      int d0 = 8 * lg + 32 * ks;
      float4 x = *(const float4*)(qp + d0);
      float4 y = *(const float4*)(qp + d0 + 4);
      u32x4 tq;
      tq[0] = cvt_pk_bf16(x.x * QSCALE, x.y * QSCALE);
      tq[1] = cvt_pk_bf16(x.z * QSCALE, x.w * QSCALE);
      tq[2] = cvt_pk_bf16(y.x * QSCALE, y.y * QSCALE);
      tq[3] = cvt_pk_bf16(y.z * QSCALE, y.w * QSCALE);
      qf[m][ks] = __builtin_bit_cast(bf16x8, tq);
    }
  }

  f32x4 o[2][8];
#pragma unroll
  for (int m = 0; m < 2; ++m)
#pragma unroll
    for (int i = 0; i < 8; ++i) o[m][i] = (f32x4){0.f, 0.f, 0.f, 0.f};
  float m_run[2], l_run[2];  // per-lane stats for q-row = m*16 + lr (S^T layout)
#pragma unroll
  for (int m = 0; m < 2; ++m) { m_run[m] = -1e30f; l_run[m] = 0.f; }

  char* pw = pbuf[w];
  const int qmax = qb * QBLK + QBLK - 1;
  const int tmax = qmax >> 6;
  const int prow_key[2] = {swz(lr), swz(16 + lr)};

  STORE_K(0);
  LOAD_T(vbase, 0);
  STORE_V(0);
  __syncthreads();

  for (int t = 0; t <= tmax; ++t) {
    const int cur = t & 1;
    const int nxt = cur ^ 1;
    const char* kb_ = kbuf[cur];
    const char* vb_ = vbuf[cur];

    if (t < tmax) LOAD_T(kbase, t + 1);  // latency hides under QK^T
    __builtin_amdgcn_sched_barrier(0);

    // ---- QK^T (SWAPPED: mfma(K, Q) -> S^T). Lane holds S[kv=16n+4lg+r][q=m16+lr].
    f32x4 s[2][4];
    __builtin_amdgcn_s_setprio(1);
#pragma unroll
    for (int n = 0; n < 4; ++n) {
      if (t * 64 + n * 16 <= qmax) {
        int krow = n * 16 + lr;
        int key = swz(krow);
        bf16x8 kb4[4];
#pragma unroll
        for (int ks = 0; ks < 4; ++ks) {
          int a0 = krow * 256 + ((16 * lg + 64 * ks) ^ key);
          bf16x4 lo = *(const bf16x4*)(kb_ + a0);
          bf16x4 hi = *(const bf16x4*)(kb_ + (a0 ^ 8));
          bf16x8 t8;
          t8[0] = lo[0]; t8[1] = lo[1]; t8[2] = lo[2]; t8[3] = lo[3];
          t8[4] = hi[0]; t8[5] = hi[1]; t8[6] = hi[2]; t8[7] = hi[3];
          kb4[ks] = t8;
        }
#pragma unroll
        for (int m = 0; m < 2; ++m) {
          f32x4 acc = {0.f, 0.f, 0.f, 0.f};
#pragma unroll
          for (int ks = 0; ks < 4; ++ks)
            acc = __builtin_amdgcn_mfma_f32_16x16x32_bf16(kb4[ks], qf[m][ks], acc, 0, 0, 0);
          s[m][n] = acc;
        }
      } else {
        s[0][n] = (f32x4){-2e30f, -2e30f, -2e30f, -2e30f};
        s[1][n] = s[0][n];
      }
    }
    __builtin_amdgcn_s_setprio(0);

    if (t < tmax) {
      STORE_K(nxt);
      LOAD_T(vbase, t + 1);
    }
    __builtin_amdgcn_sched_barrier(0);

    // ---- causal mask on diagonal tile: kv = t*64+16n+4lg+r, q = qb*32+m16+lr ----
    if (t == tmax) {
#pragma unroll
      for (int n = 0; n < 4; ++n) {
        int kv_pos = t * 64 + n * 16 + 4 * lg;
#pragma unroll
        for (int m = 0; m < 2; ++m) {
          int qrow = qb * QBLK + m * 16 + lr;
#pragma unroll
          for (int r = 0; r < 4; ++r)
            if (kv_pos + r > qrow) s[m][n][r] = -2e30f;
        }
      }
    }

    // ---- online softmax in S^T: per-lane row reduce + 2 shfls ----
#pragma unroll
    for (int m = 0; m < 2; ++m) {
      float mx = fmaxf(
          fmaxf(fmaxf(fmaxf(s[m][0][0], s[m][0][1]), fmaxf(s[m][0][2], s[m][0][3])),
                fmaxf(fmaxf(s[m][1][0], s[m][1][1]), fmaxf(s[m][1][2], s[m][1][3]))),
          fmaxf(fmaxf(fmaxf(s[m][2][0], s[m][2][1]), fmaxf(s[m][2][2], s[m][2][3])),
                fmaxf(fmaxf(s[m][3][0], s[m][3][1]), fmaxf(s[m][3][2], s[m][3][3]))));
      mx = fmaxf(mx, __shfl_xor(mx, 16, 64));
      mx = fmaxf(mx, __shfl_xor(mx, 32, 64));
      if (!__all(mx - m_run[m] <= 10.0f)) {  // T13 defer-max: P bounded by 2^10
        float mn = fmaxf(m_run[m], mx);
        float corr = exp2f(m_run[m] - mn);
        m_run[m] = mn;
        l_run[m] *= corr;
        float cr[4];
#pragma unroll
        for (int r = 0; r < 4; ++r) cr[r] = __shfl(corr, 4 * lg + r, 64);
#pragma unroll
        for (int dt = 0; dt < 8; ++dt)
#pragma unroll
          for (int r = 0; r < 4; ++r) o[m][dt][r] *= cr[r];
      }
      float rsum = 0.f;
#pragma unroll
      for (int n = 0; n < 4; ++n) {
        float p0 = exp2f(s[m][n][0] - m_run[m]);
        float p1 = exp2f(s[m][n][1] - m_run[m]);
        float p2 = exp2f(s[m][n][2] - m_run[m]);
        float p3 = exp2f(s[m][n][3] - m_run[m]);
        rsum += (p0 + p1) + (p2 + p3);
        u32x2 pk;
        pk[0] = cvt_pk_bf16(p0, p1);
        pk[1] = cvt_pk_bf16(p2, p3);
        // contiguous kv run: P[q=m16+lr][kv=16n+4lg .. +3], one 8B write
        *(u32x2*)(pw + (m * 16 + lr) * 128 + ((32 * n + 8 * lg) ^ prow_key[m])) = pk;
      }
      rsum += __shfl_xor(rsum, 16, 64);
      rsum += __shfl_xor(rsum, 32, 64);
      l_run[m] += rsum;
    }

    // ---- PV: O[32 q][128 d] += P[32][64] * V[64][128]; skip dead half ----
    const int nks = (t * 64 + 32 <= qmax) ? 2 : 1;
    __builtin_amdgcn_s_setprio(1);
    for (int ks = 0; ks < nks; ++ks) {
      bf16x8 pa[2];
#pragma unroll
      for (int m = 0; m < 2; ++m) {
        int a0 = (m * 16 + lr) * 128 + ((16 * lg + 64 * ks) ^ prow_key[m]);
        bf16x4 lo = *(const bf16x4*)(pw + a0);
        bf16x4 hi = *(const bf16x4*)(pw + (a0 ^ 8));
        bf16x8 t8;
        t8[0] = lo[0]; t8[1] = lo[1]; t8[2] = lo[2]; t8[3] = lo[3];
        t8[4] = hi[0]; t8[5] = hi[1]; t8[6] = hi[2]; t8[7] = hi[3];
        pa[m] = t8;
      }
#pragma unroll
      for (int dt = 0; dt < 8; ++dt) {
        int d = dt * 16 + lr;
        int a0 = d * 128 + ((16 * lg + 64 * ks) ^ swz(d));
        bf16x4 lo = *(const bf16x4*)(vb_ + a0);
        bf16x4 hi = *(const bf16x4*)(vb_ + (a0 ^ 8));
        bf16x8 vbf;
        vbf[0] = lo[0]; vbf[1] = lo[1]; vbf[2] = lo[2]; vbf[3] = lo[3];
        vbf[4] = hi[0]; vbf[5] = hi[1]; vbf[6] = hi[2]; vbf[7] = hi[3];
#pragma unroll
        for (int m = 0; m < 2; ++m)
          o[m][dt] = __builtin_amdgcn_mfma_f32_16x16x32_bf16(pa[m], vbf, o[m][dt], 0, 0, 0);
      }
    }
    __builtin_amdgcn_s_setprio(0);

    if (t < tmax) STORE_V(nxt);
    __syncthreads();  // ONE barrier per tile
  }

  // ---- epilogue: O rows live at q = 4lg+r; stats at q = lr -> shfl transpose ----
#pragma unroll
  for (int m = 0; m < 2; ++m) {
    float linv[4];
#pragma unroll
    for (int r = 0; r < 4; ++r) linv[r] = 1.0f / __shfl(l_run[m], 4 * lg + r, 64);
#pragma unroll
    for (int r = 0; r < 4; ++r) {
      int qp_ = qb * QBLK + m * 16 + 4 * lg + r;
      if (qp_ < seq_len) {
        float* op = out + (size_t)(seq_start + qp_) * (H * DD) + h * DD + lr;
#pragma unroll
        for (int dt = 0; dt < 8; ++dt) op[dt * 16] = o[m][dt][r] * linv[r];
      }
    }
  }
#undef LOAD_T
#undef STORE_K
#undef STORE_V
}

extern "C" void kernel_launch(void* const* d_in, const int* in_sizes, int n_in,
                              void* d_out, int out_size, void* d_ws, size_t ws_size,
                              hipStream_t stream) {
  const float* q = (const float*)d_in[0];
  const float* k = (const float*)d_in[1];
  const float* v = (const float*)d_in[2];
  const int* cu = (const int*)d_in[3];
  float* out = (float*)d_out;
  const int B = in_sizes[3] - 1;  // 4
  const int inner_n = B * HKV;    // 32
  dim3 grid(NQB * inner_n);       // 1024 blocks, qb descending-major
  fa_kernel<<<grid, 256, 0, stream>>>(q, k, v, cu, out, inner_n);
}